// Round 16
// baseline (5443.040 us; speedup 1.0000x reference)
//
#include <hip/hip_runtime.h>

// Recurrent spiking LIF network: T=64, B=32, NE=4096, NI=1024, N=5120.
// fp64 accumulation => spike-identical to fp64 numpy ref (rounds 2-15: 0.0).
//
// Round-16: r15 with ONE surgical change: the spike multiplicand is now
// a uniform ternary of compile-time constants (1.0 : 0.0) instead of
// (double)((m>>j)&1). r15's 30us/step of v_cvt_f64_u32 becomes SALU
// s_cselect_b64, and v_fma_f64 reads the SGPR pair directly -> the
// vector pipe runs pure FMA (21.3us/step floor).
//  - everything else byte-identical to r15: G=32 k-split, 1280 blocks =
//    5/CU, 16 KB LDS weight tiles via global_load_lds (FETCH 52 MB),
//    spike bitmasks via readfirstlane, proven upd/pack kernels.

#define NE 4096
#define NI 1024
#define NN 5120
#define HN 2560
#define BB 32
#define CHUNK 32

typedef unsigned int u32;

__device__ __forceinline__ void load_lds16(const float* g, float* l) {
    __builtin_amdgcn_global_load_lds(
        (const __attribute__((address_space(1))) u32*)g,
        (__attribute__((address_space(3))) u32*)l, 16, 0, 0);
}

// ---------------- spike pack kernel ----------------
__global__ __launch_bounds__(256) void pack_kernel(
    const float* __restrict__ out_t, u32* __restrict__ mask)
{
    const int n = blockIdx.x * 256 + threadIdx.x;   // NN = 20*256 exact
    u32 m = 0;
#pragma unroll
    for (int b = 0; b < BB; ++b)
        m |= (out_t[(size_t)b * NN + n] > 0.5f ? 1u : 0u) << b;
    mask[n] = m;
}

// ---------------- matvec partial kernel ----------------
// grid: (HN/64, G), block 256 = 64 n-lanes x 4 j-groups(8 batches).
// Thread owns neurons {nA = bx*64+lane, nA+2560} x batches [jh, jh+8).
template <int G>
__global__ __launch_bounds__(256) void mv_kernel(
    const float* __restrict__ W_ee, const float* __restrict__ W_ei,
    const float* __restrict__ W_ie, const float* __restrict__ W_ii,
    const u32* __restrict__ mask,    // [NN] spike bitmasks (bit b = batch b)
    double* __restrict__ partial)    // [G][BB][NN]
{
    constexpr int KR = NN / G;
    __shared__ __align__(16) float tile[16 * 256];   // 16 slots x 64 lanes x 16B
    const int tid  = threadIdx.x;
    const int lane = tid & 63;
    const int wv   = tid >> 6;
    const int jh   = wv << 3;                  // 0,8,16,24
    const int nA   = blockIdx.x * 64 + lane;   // < HN (E-target half)
    const int kb0  = blockIdx.y * KR;

    // block-uniform weight-row bases for the two n-halves
    const int n0 = blockIdx.x * 64;
    const int n1 = n0 + HN;
    const bool h1E = (n1 < NE);
    const float* e0 = W_ee + (size_t)n0 * NE;
    const float* e1 = h1E ? (W_ee + (size_t)n1 * NE) : (W_ei + (size_t)(n1 - NE) * NE);
    const float* i0 = W_ie + (size_t)n0 * NI;
    const float* i1 = h1E ? (W_ie + (size_t)n1 * NI) : (W_ii + (size_t)(n1 - NE) * NI);

    double accA[8], accB[8];
#pragma unroll
    for (int j = 0; j < 8; ++j) { accA[j] = 0.0; accB[j] = 0.0; }

    for (int ch = 0; ch < KR / CHUNK; ++ch) {
        const int kb = kb0 + ch * CHUNK;       // 32 | NE -> pure E or I segment
        const bool eseg = (kb < NE);
        const int kloc = eseg ? kb : kb - NE;
        const size_t kdim = eseg ? NE : NI;
        const float* b0 = eseg ? e0 : i0;
        const float* b1 = eseg ? e1 : i1;

        if (ch) __syncthreads();               // protect tile overwrite
        // stage 128 rows x 32 k: 16 slots of (64 lanes x 16B); 4 per wave.
#pragma unroll
        for (int c = 0; c < 4; ++c) {
            const int slot = wv * 4 + c;
            const int q = slot >> 1;
            const float* base = (slot & 1) ? b1 : b0;
            load_lds16(base + (size_t)lane * kdim + (kloc + q * 4),
                       &tile[slot * 256]);
        }
        __syncthreads();                       // drains vmcnt -> tile valid

#pragma unroll
        for (int q = 0; q < 8; ++q) {
            const float4 wa = *reinterpret_cast<const float4*>(&tile[(q * 2 + 0) * 256 + lane * 4]);
            const float4 wb = *reinterpret_cast<const float4*>(&tile[(q * 2 + 1) * 256 + lane * 4]);
            const uint4 mq = *reinterpret_cast<const uint4*>(&mask[kb + q * 4]);
            const u32 m0 = ((u32)__builtin_amdgcn_readfirstlane(mq.x)) >> jh;
            const u32 m1 = ((u32)__builtin_amdgcn_readfirstlane(mq.y)) >> jh;
            const u32 m2 = ((u32)__builtin_amdgcn_readfirstlane(mq.z)) >> jh;
            const u32 m3 = ((u32)__builtin_amdgcn_readfirstlane(mq.w)) >> jh;

            const double wa0 = (double)wa.x, wa1 = (double)wa.y,
                         wa2 = (double)wa.z, wa3 = (double)wa.w;
            const double wb0 = (double)wb.x, wb1 = (double)wb.y,
                         wb2 = (double)wb.z, wb3 = (double)wb.w;
#pragma unroll
            for (int j = 0; j < 8; ++j) {
                // uniform bit -> SALU s_cselect_b64 of {1.0, 0.0}; FMA reads
                // the SGPR pair directly (no vector cvt on the VALU pipe).
                const double s0 = (m0 & (1u << j)) ? 1.0 : 0.0;
                const double s1 = (m1 & (1u << j)) ? 1.0 : 0.0;
                const double s2 = (m2 & (1u << j)) ? 1.0 : 0.0;
                const double s3 = (m3 & (1u << j)) ? 1.0 : 0.0;
                accA[j] += wa0 * s0 + wa1 * s1 + wa2 * s2 + wa3 * s3;
                accB[j] += wb0 * s0 + wb1 * s1 + wb2 * s2 + wb3 * s3;
            }
        }
    }

#pragma unroll
    for (int j = 0; j < 8; ++j) {
        const size_t base = ((size_t)blockIdx.y * BB + jh + j) * NN;
        partial[base + nA] = accA[j];
        partial[base + nA + HN] = accB[j];
    }
}

// ---------------- LIF update kernel ----------------
template <int G>
__global__ __launch_bounds__(256) void upd_kernel(
    const float* __restrict__ ext_exc,   // [T][BB][NE]
    const float* __restrict__ ext_inh,   // [T][BB][NI]
    const double* __restrict__ partial,  // [G][BB][NN]
    double* __restrict__ v,              // [BB][NN]
    float* __restrict__ out,             // [T][BB][NN]
    int t)
{
    const int idx = blockIdx.x * 256 + threadIdx.x;   // < BB*NN
    const int b = idx / NN;
    const int n = idx - b * NN;

    const float ext = (n < NE)
        ? ext_exc[((size_t)t * BB + b) * NE + n]
        : ext_inh[((size_t)t * BB + b) * NI + (n - NE)];

    double acc = (double)ext;
#pragma unroll
    for (int g = 0; g < G; ++g)
        acc += partial[((size_t)g * BB + b) * NN + n];

    const double vv = v[idx] * 0.9 + acc;
    const double sp = (vv > 1.0) ? 1.0 : 0.0;
    out[(size_t)t * BB * NN + idx] = (float)sp;
    v[idx] = vv * (1.0 - sp);
}

extern "C" void kernel_launch(void* const* d_in, const int* in_sizes, int n_in,
                              void* d_out, int out_size, void* d_ws, size_t ws_size,
                              hipStream_t stream) {
    const float* ext_exc = (const float*)d_in[0];
    const float* ext_inh = (const float*)d_in[1];
    const float* W_ee = (const float*)d_in[2];
    const float* W_ei = (const float*)d_in[3];
    const float* W_ie = (const float*)d_in[4];
    const float* W_ii = (const float*)d_in[5];
    float* out = (float*)d_out;

    const int T = in_sizes[0] / (BB * NE);   // 64

    const size_t SN = (size_t)BB * NN;       // 163840
    double* v = (double*)d_ws;               // SN*8
    u32* mask = (u32*)(v + SN);              // NN*4
    const size_t stateBytes = SN * 8 + (size_t)NN * 4;   // ~1.33 MB
    double* partial = (double*)((char*)d_ws + stateBytes);

    // G=32 preferred (41.9 MB partial; proven fit in rounds 2/5/9/15).
    int G = 32;
    if (stateBytes + (size_t)G * SN * sizeof(double) > ws_size) G = 16;

    hipMemsetAsync(d_ws, 0, stateBytes, stream);   // v = 0, mask = 0

    for (int t = 0; t < T; ++t) {
        if (G == 32) {
            mv_kernel<32><<<dim3(HN / 64, 32), 256, 0, stream>>>(
                W_ee, W_ei, W_ie, W_ii, mask, partial);
            upd_kernel<32><<<(int)(SN / 256), 256, 0, stream>>>(
                ext_exc, ext_inh, partial, v, out, t);
        } else {
            mv_kernel<16><<<dim3(HN / 64, 16), 256, 0, stream>>>(
                W_ee, W_ei, W_ie, W_ii, mask, partial);
            upd_kernel<16><<<(int)(SN / 256), 256, 0, stream>>>(
                ext_exc, ext_inh, partial, v, out, t);
        }
        pack_kernel<<<NN / 256, 256, 0, stream>>>(out + (size_t)t * SN, mask);
    }
}

// Round 17
// 4859.937 us; speedup vs baseline: 1.1200x; 1.1200x over previous
//
#include <hip/hip_runtime.h>

// Recurrent spiking LIF network: T=64, B=32, NE=4096, NI=1024, N=5120.
// fp64 accumulation => spike-identical to fp64 numpy ref (rounds 2-16: 0.0).
//
// Round-17: r15 core + DOUBLE-BUFFERED weight tiles (2-phase pipeline).
//  - r16 lesson: the (bit ? 1.0 : 0.0) ternary compiles to v_cndmask pairs
//    (VALU 82%, slower). Reverted to the shared v_cvt_f64_u32 form.
//  - r15 structure was stage->barrier->compute: hipcc emits vmcnt(0)
//    right before s_barrier, exposing full global->LDS latency per chunk.
//    Now: barrier -> stage(next chunk, other buffer) -> compute(current).
//    Loads land under the ~1600cy compute phase; the drain at the next
//    barrier is nearly free. LDS 2x16KB = 32KB -> still 5 blocks/CU.
//  - everything else identical: G=32, grid (40,32) = 5 blocks/CU,
//    global_load_lds staging, bitmask spikes in SGPRs, upd/pack proven.

#define NE 4096
#define NI 1024
#define NN 5120
#define HN 2560
#define BB 32
#define CHUNK 32

typedef unsigned int u32;

__device__ __forceinline__ void load_lds16(const float* g, float* l) {
    __builtin_amdgcn_global_load_lds(
        (const __attribute__((address_space(1))) u32*)g,
        (__attribute__((address_space(3))) u32*)l, 16, 0, 0);
}

// ---------------- spike pack kernel ----------------
__global__ __launch_bounds__(256) void pack_kernel(
    const float* __restrict__ out_t, u32* __restrict__ mask)
{
    const int n = blockIdx.x * 256 + threadIdx.x;   // NN = 20*256 exact
    u32 m = 0;
#pragma unroll
    for (int b = 0; b < BB; ++b)
        m |= (out_t[(size_t)b * NN + n] > 0.5f ? 1u : 0u) << b;
    mask[n] = m;
}

// ---------------- matvec partial kernel ----------------
// grid: (HN/64, G), block 256 = 64 n-lanes x 4 j-groups(8 batches).
// Thread owns neurons {nA = bx*64+lane, nA+2560} x batches [jh, jh+8).
template <int G>
__global__ __launch_bounds__(256) void mv_kernel(
    const float* __restrict__ W_ee, const float* __restrict__ W_ei,
    const float* __restrict__ W_ie, const float* __restrict__ W_ii,
    const u32* __restrict__ mask,    // [NN] spike bitmasks (bit b = batch b)
    double* __restrict__ partial)    // [G][BB][NN]
{
    constexpr int KR = NN / G;
    constexpr int NCH = KR / CHUNK;            // chunks per block (5 at G=32)
    __shared__ __align__(16) float tile[2][16 * 256];   // 2 x 16 KB
    const int tid  = threadIdx.x;
    const int lane = tid & 63;
    const int wv   = tid >> 6;
    const int jh   = wv << 3;                  // 0,8,16,24
    const int nA   = blockIdx.x * 64 + lane;   // < HN (E-target half)
    const int kb0  = blockIdx.y * KR;

    // block-uniform weight-row bases for the two n-halves
    const int n0 = blockIdx.x * 64;
    const int n1 = n0 + HN;
    const bool h1E = (n1 < NE);
    const float* e0 = W_ee + (size_t)n0 * NE;
    const float* e1 = h1E ? (W_ee + (size_t)n1 * NE) : (W_ei + (size_t)(n1 - NE) * NE);
    const float* i0 = W_ie + (size_t)n0 * NI;
    const float* i1 = h1E ? (W_ie + (size_t)n1 * NI) : (W_ii + (size_t)(n1 - NE) * NI);

    double accA[8], accB[8];
#pragma unroll
    for (int j = 0; j < 8; ++j) { accA[j] = 0.0; accB[j] = 0.0; }

    // stage chunk ch's 128 rows x 32 k into tile[buf]:
    // 16 slots of (64 lanes x 16B); 4 slots per wave. slot = q*2 + half.
    auto stage = [&](int ch, int buf) {
        const int kb = kb0 + ch * CHUNK;       // 32 | NE -> pure E or I segment
        const bool eseg = (kb < NE);
        const int kloc = eseg ? kb : kb - NE;
        const size_t kdim = eseg ? NE : NI;
        const float* b0 = eseg ? e0 : i0;
        const float* b1 = eseg ? e1 : i1;
#pragma unroll
        for (int c = 0; c < 4; ++c) {
            const int slot = wv * 4 + c;
            const int q = slot >> 1;
            const float* base = (slot & 1) ? b1 : b0;
            load_lds16(base + (size_t)lane * kdim + (kloc + q * 4),
                       &tile[buf][slot * 256]);
        }
    };

    stage(0, 0);                               // prologue (latency exposed once)

    for (int ch = 0; ch < NCH; ++ch) {
        const int cur = ch & 1;
        __syncthreads();                       // tile[cur] loads drained here
        if (ch + 1 < NCH) stage(ch + 1, cur ^ 1);   // fly under compute

        const int kb = kb0 + ch * CHUNK;
#pragma unroll
        for (int q = 0; q < 8; ++q) {
            const float4 wa = *reinterpret_cast<const float4*>(&tile[cur][(q * 2 + 0) * 256 + lane * 4]);
            const float4 wb = *reinterpret_cast<const float4*>(&tile[cur][(q * 2 + 1) * 256 + lane * 4]);
            const uint4 mq = *reinterpret_cast<const uint4*>(&mask[kb + q * 4]);
            const u32 m0 = ((u32)__builtin_amdgcn_readfirstlane(mq.x)) >> jh;
            const u32 m1 = ((u32)__builtin_amdgcn_readfirstlane(mq.y)) >> jh;
            const u32 m2 = ((u32)__builtin_amdgcn_readfirstlane(mq.z)) >> jh;
            const u32 m3 = ((u32)__builtin_amdgcn_readfirstlane(mq.w)) >> jh;

            const double wa0 = (double)wa.x, wa1 = (double)wa.y,
                         wa2 = (double)wa.z, wa3 = (double)wa.w;
            const double wb0 = (double)wb.x, wb1 = (double)wb.y,
                         wb2 = (double)wb.z, wb3 = (double)wb.w;
#pragma unroll
            for (int j = 0; j < 8; ++j) {
                const double s0 = (double)((m0 >> j) & 1u);
                const double s1 = (double)((m1 >> j) & 1u);
                const double s2 = (double)((m2 >> j) & 1u);
                const double s3 = (double)((m3 >> j) & 1u);
                accA[j] += wa0 * s0 + wa1 * s1 + wa2 * s2 + wa3 * s3;
                accB[j] += wb0 * s0 + wb1 * s1 + wb2 * s2 + wb3 * s3;
            }
        }
    }

#pragma unroll
    for (int j = 0; j < 8; ++j) {
        const size_t base = ((size_t)blockIdx.y * BB + jh + j) * NN;
        partial[base + nA] = accA[j];
        partial[base + nA + HN] = accB[j];
    }
}

// ---------------- LIF update kernel ----------------
template <int G>
__global__ __launch_bounds__(256) void upd_kernel(
    const float* __restrict__ ext_exc,   // [T][BB][NE]
    const float* __restrict__ ext_inh,   // [T][BB][NI]
    const double* __restrict__ partial,  // [G][BB][NN]
    double* __restrict__ v,              // [BB][NN]
    float* __restrict__ out,             // [T][BB][NN]
    int t)
{
    const int idx = blockIdx.x * 256 + threadIdx.x;   // < BB*NN
    const int b = idx / NN;
    const int n = idx - b * NN;

    const float ext = (n < NE)
        ? ext_exc[((size_t)t * BB + b) * NE + n]
        : ext_inh[((size_t)t * BB + b) * NI + (n - NE)];

    double acc = (double)ext;
#pragma unroll
    for (int g = 0; g < G; ++g)
        acc += partial[((size_t)g * BB + b) * NN + n];

    const double vv = v[idx] * 0.9 + acc;
    const double sp = (vv > 1.0) ? 1.0 : 0.0;
    out[(size_t)t * BB * NN + idx] = (float)sp;
    v[idx] = vv * (1.0 - sp);
}

extern "C" void kernel_launch(void* const* d_in, const int* in_sizes, int n_in,
                              void* d_out, int out_size, void* d_ws, size_t ws_size,
                              hipStream_t stream) {
    const float* ext_exc = (const float*)d_in[0];
    const float* ext_inh = (const float*)d_in[1];
    const float* W_ee = (const float*)d_in[2];
    const float* W_ei = (const float*)d_in[3];
    const float* W_ie = (const float*)d_in[4];
    const float* W_ii = (const float*)d_in[5];
    float* out = (float*)d_out;

    const int T = in_sizes[0] / (BB * NE);   // 64

    const size_t SN = (size_t)BB * NN;       // 163840
    double* v = (double*)d_ws;               // SN*8
    u32* mask = (u32*)(v + SN);              // NN*4
    const size_t stateBytes = SN * 8 + (size_t)NN * 4;   // ~1.33 MB
    double* partial = (double*)((char*)d_ws + stateBytes);

    // G=32 preferred (41.9 MB partial; proven fit in rounds 2/5/9/15).
    int G = 32;
    if (stateBytes + (size_t)G * SN * sizeof(double) > ws_size) G = 16;

    hipMemsetAsync(d_ws, 0, stateBytes, stream);   // v = 0, mask = 0

    for (int t = 0; t < T; ++t) {
        if (G == 32) {
            mv_kernel<32><<<dim3(HN / 64, 32), 256, 0, stream>>>(
                W_ee, W_ei, W_ie, W_ii, mask, partial);
            upd_kernel<32><<<(int)(SN / 256), 256, 0, stream>>>(
                ext_exc, ext_inh, partial, v, out, t);
        } else {
            mv_kernel<16><<<dim3(HN / 64, 16), 256, 0, stream>>>(
                W_ee, W_ei, W_ie, W_ii, mask, partial);
            upd_kernel<16><<<(int)(SN / 256), 256, 0, stream>>>(
                ext_exc, ext_inh, partial, v, out, t);
        }
        pack_kernel<<<NN / 256, 256, 0, stream>>>(out + (size_t)t * SN, mask);
    }
}